// Round 8
// baseline (13069.604 us; speedup 1.0000x reference)
//
#include <hip/hip_runtime.h>
#include <hip/hip_fp16.h>
#include <stdint.h>

// LSTM-like scan, T=4096, E=1024, H=1024.
// Phase 1: xpre4[t][row][g] = (x @ U_g^T + B_g)  fp16, gate-interleaved
// Phase 2: persistent 64-WG x 512-thread kernel, 16 rows/WG, self-poll sync
//   with 8-WAY REPLICATED tagged h buffers (herd-splitting):
//     - leaders publish ((t+1)<<16)|fp16(h) to ALL nrep replicas (sc0sc1)
//     - WG wg polls ONLY replica wg&(nrep-1): per-line reader herd at the
//       coherence point drops nrep x (R7 evidence: step time scales with
//       same-line poller count, 32WG=1.7us 64WG=2.8us 256WG=5us)
//   Per step per lane: issue 16 coalesced weight dwordx4 loads (overlap with
//   poll's vmcnt(0)); poll own u64 pair; LDS; one barrier; 16 conflict-free
//   ds_reads + 64 v_dot2; 5-level shfl reduce; leader epilogue + publish.

#define T_STEPS 4096
#define HDIM 1024
#define NWG 64

typedef _Float16 half2v __attribute__((ext_vector_type(2)));
typedef uint32_t u32x4 __attribute__((ext_vector_type(4)));

__device__ __forceinline__ float dot2(uint32_t a, uint32_t b, float c) {
#if __has_builtin(__builtin_amdgcn_fdot2)
  return __builtin_amdgcn_fdot2(__builtin_bit_cast(half2v, a),
                                __builtin_bit_cast(half2v, b), c, false);
#else
  half2v av = __builtin_bit_cast(half2v, a);
  half2v bv = __builtin_bit_cast(half2v, b);
  return c + (float)av.x * (float)bv.x + (float)av.y * (float)bv.y;
#endif
}

__device__ __forceinline__ float sigf(float z) { return 1.f / (1.f + __expf(-z)); }

// ---- weight repack: gate f32 [1024][1024] x4 -> rnnk's coalesced layout ----
// dst dword index o = ((wg*16 + j)*512 + tid)*4 + e :
//   lane (wg,tid): k=tid&31, rloc=tid>>5, row=wg*16+rloc
//   logical weight dword i = 4j+e in [0,64): gate g=i>>4, n=i&15,
//   h-pair p = k + 32n  -> cols 2p, 2p+1 of gate-g weight row `row`.
__global__ __launch_bounds__(256) void convw(const float* __restrict__ w0,
                                             const float* __restrict__ w1,
                                             const float* __restrict__ w2,
                                             const float* __restrict__ w3,
                                             uint32_t* __restrict__ dst) {
  int o = blockIdx.x * 256 + threadIdx.x;  // 0 .. 2M-1
  int e = o & 3;
  int tid = (o >> 2) & 511;
  int j = (o >> 11) & 15;
  int wg = o >> 15;
  int i = 4 * j + e;
  int g = i >> 4, n = i & 15;
  int k = tid & 31, rloc = tid >> 5;
  int row = (wg << 4) + rloc;
  int col = ((k + (n << 5)) << 1);
  const float* src = g == 0 ? w0 : g == 1 ? w1 : g == 2 ? w2 : w3;
  float2 v = *(const float2*)(src + (size_t)row * 1024 + col);
  dst[o] = (uint32_t)__half_as_ushort(__float2half(v.x)) |
           ((uint32_t)__half_as_ushort(__float2half(v.y)) << 16);
}

// -------- zero the replicated tagged buffers (nrep x 2 x 1024 dwords) ---------
__global__ void zerok(uint32_t* __restrict__ p, int n) {
  int i = blockIdx.x * 256 + threadIdx.x;
  if (i < n) p[i] = 0;
}

// ---------------- fp32 GEMM: xpre4[t][j][g] = x[t][:] . U_g[j][:] + B_g[j] -----
__global__ __launch_bounds__(256) void gemmk(
    const float* __restrict__ x,
    const float* __restrict__ u0, const float* __restrict__ u1,
    const float* __restrict__ u2, const float* __restrict__ u3,
    const float* __restrict__ b0, const float* __restrict__ b1,
    const float* __restrict__ b2, const float* __restrict__ b3,
    __half* __restrict__ xpre4) {
  __shared__ float As[64][33];
  __shared__ float Bs[64][33];
  const int tid = threadIdx.x;
  const int m0 = blockIdx.y * 64;
  const int n0 = blockIdx.x * 64;
  const int g = n0 >> 10;
  const float* Up = g == 0 ? u0 : g == 1 ? u1 : g == 2 ? u2 : u3;
  const float* Bp = g == 0 ? b0 : g == 1 ? b1 : g == 2 ? b2 : b3;
  const int j0 = n0 & 1023;
  const int tx = tid & 15, ty = tid >> 4;
  const int lr = tid >> 3, lc = (tid & 7) << 2;
  float acc[4][4] = {};
  for (int k0 = 0; k0 < 1024; k0 += 32) {
    float4 a0 = *(const float4*)&x[(size_t)(m0 + lr) * 1024 + k0 + lc];
    float4 a1 = *(const float4*)&x[(size_t)(m0 + lr + 32) * 1024 + k0 + lc];
    float4 c0 = *(const float4*)&Up[(size_t)(j0 + lr) * 1024 + k0 + lc];
    float4 c1 = *(const float4*)&Up[(size_t)(j0 + lr + 32) * 1024 + k0 + lc];
    __syncthreads();
    As[lr][lc + 0] = a0.x; As[lr][lc + 1] = a0.y; As[lr][lc + 2] = a0.z; As[lr][lc + 3] = a0.w;
    As[lr + 32][lc + 0] = a1.x; As[lr + 32][lc + 1] = a1.y; As[lr + 32][lc + 2] = a1.z; As[lr + 32][lc + 3] = a1.w;
    Bs[lr][lc + 0] = c0.x; Bs[lr][lc + 1] = c0.y; Bs[lr][lc + 2] = c0.z; Bs[lr][lc + 3] = c0.w;
    Bs[lr + 32][lc + 0] = c1.x; Bs[lr + 32][lc + 1] = c1.y; Bs[lr + 32][lc + 2] = c1.z; Bs[lr + 32][lc + 3] = c1.w;
    __syncthreads();
#pragma unroll
    for (int k = 0; k < 32; ++k) {
      float a0v = As[ty * 4 + 0][k], a1v = As[ty * 4 + 1][k];
      float a2v = As[ty * 4 + 2][k], a3v = As[ty * 4 + 3][k];
      float b0v = Bs[tx * 4 + 0][k], b1v = Bs[tx * 4 + 1][k];
      float b2v = Bs[tx * 4 + 2][k], b3v = Bs[tx * 4 + 3][k];
      acc[0][0] += a0v * b0v; acc[0][1] += a0v * b1v; acc[0][2] += a0v * b2v; acc[0][3] += a0v * b3v;
      acc[1][0] += a1v * b0v; acc[1][1] += a1v * b1v; acc[1][2] += a1v * b2v; acc[1][3] += a1v * b3v;
      acc[2][0] += a2v * b0v; acc[2][1] += a2v * b1v; acc[2][2] += a2v * b2v; acc[2][3] += a2v * b3v;
      acc[3][0] += a3v * b0v; acc[3][1] += a3v * b1v; acc[3][2] += a3v * b2v; acc[3][3] += a3v * b3v;
    }
  }
  // scatter epilogue: xpre4[(t*1024 + j)*4 + g]
#pragma unroll
  for (int i = 0; i < 4; ++i) {
    size_t rowi = (size_t)(m0 + ty * 4 + i);
#pragma unroll
    for (int j = 0; j < 4; ++j) {
      int jj = j0 + tx * 4 + j;
      float v = acc[i][j] + Bp[jj];
      xpre4[(rowi * 1024 + jj) * 4 + g] = __float2half(v);
    }
  }
}

// ---------------- persistent recurrence kernel --------------------------------
// tagged: nrep replicas, each [2][1024] dwords, replica stride 2048 dwords.
__global__ __launch_bounds__(512, 1) void rnnk(
    const uint32_t* __restrict__ wpack,  // [64][16][512][4] dwords (see convw)
    const __half* __restrict__ xpre4,    // [4096][1024][4] fp16
    uint32_t* tagged,                    // [nrep][2][1024] tagged h dwords
    float* __restrict__ out,             // [4096][1024] f32
    int repmask) {                       // nrep-1 (nrep = pow2 <= 8)
  __shared__ uint32_t hl[2][512];        // packed h pairs, linear
  const int wg = blockIdx.x;
  const int tid = threadIdx.x;
  const int k = tid & 31;            // h-chunk lane
  const int rloc = tid >> 5;         // 0..15
  const int row = (wg << 4) + rloc;  // 0..1023
  const bool leader = (k == 0);

  const uint32_t* wbase = wpack + (((size_t)wg << 4) << 11) + (tid << 2);
  uint32_t* myrep = tagged + ((size_t)(wg & repmask) << 11);  // poll replica

  float s = 0.f;  // cell state (leader lanes only)

  for (int t = 0; t < T_STEPS; ++t) {
    const int buf = t & 1;

    // --- 1. issue this step's 16 weight loads (coalesced; no wait here) ---
    u32x4 wq[16];
#pragma unroll
    for (int j = 0; j < 16; ++j) {
      const uint32_t* p = wbase + (j << 11);
      asm volatile("global_load_dwordx4 %0, %1, off" : "=v"(wq[j]) : "v"(p));
    }

    // --- 2. leader prefetch of the 4 gate pre-activations (8B) ---
    float xf = 0.f, xc = 0.f, xg = 0.f, xq = 0.f;
    if (leader) {
      uint2 xv = *reinterpret_cast<const uint2*>(
          reinterpret_cast<const uint32_t*>(xpre4) +
          ((((size_t)t << 10) + row) << 1));
      __half2 lo = __builtin_bit_cast(__half2, xv.x);
      __half2 hi = __builtin_bit_cast(__half2, xv.y);
      xf = __half2float(lo.x); xc = __half2float(lo.y);
      xg = __half2float(hi.x); xq = __half2float(hi.y);
    }

    // --- 3. self-poll own tagged pair in OUR replica; vmcnt(0) drains weights ---
    {
      const unsigned long long* pp =
          reinterpret_cast<const unsigned long long*>(myrep + (buf << 10)) + tid;
      const uint32_t tg = (uint32_t)t;
      unsigned long long v;
      for (;;) {
        asm volatile(
            "global_load_dwordx2 %0, %1, off sc0 sc1\n\t"
            "s_waitcnt vmcnt(0)"
            : "=v"(v) : "v"(pp) : "memory");
        if ((((uint32_t)(v >> 16) & 0xffffu) == tg) && ((uint32_t)(v >> 48) == tg))
          break;
        __builtin_amdgcn_s_sleep(1);
      }
      hl[buf][tid] = (uint32_t)(v & 0xffffu) |
                     (((uint32_t)(v >> 32) & 0xffffu) << 16);
    }
    __syncthreads();  // hl[buf] ready — the only barrier per step

    // --- 4. h pairs at lane-stride 32 (bank = k: conflict-free) + 64 dot2 ---
    uint32_t hp[16];
#pragma unroll
    for (int n = 0; n < 16; ++n) hp[n] = hl[buf][k + (n << 5)];

#define WD(g, n) (wq[((g)*16 + (n)) >> 2][((g)*16 + (n)) & 3])
    float a0 = 0.f, a1 = 0.f, a2 = 0.f, a3 = 0.f;
#pragma unroll
    for (int n = 0; n < 16; ++n) {
      a0 = dot2(WD(0, n), hp[n], a0);
      a1 = dot2(WD(1, n), hp[n], a1);
      a2 = dot2(WD(2, n), hp[n], a2);
      a3 = dot2(WD(3, n), hp[n], a3);
    }
#undef WD

    // --- 5. reduce across the 32 chunk-lanes (stays within 32-lane halves) ---
#pragma unroll
    for (int mk = 1; mk <= 16; mk <<= 1) {
      a0 += __shfl_xor(a0, mk);
      a1 += __shfl_xor(a1, mk);
      a2 += __shfl_xor(a2, mk);
      a3 += __shfl_xor(a3, mk);
    }

    // --- leader epilogue: gates, s-update, h, publish to ALL replicas ---
    if (leader) {
      float f = sigf(a0 + xf);
      float cc = sigf(a1 + xc);
      float gg = sigf(a2 + xg);
      float q = sigf(a3 + xq);
      s = f * s + gg * cc;
      float e2 = __expf(2.f * s);  // s >= 0 always; inf -> th = 1
      float th = 1.f - 2.f / (e2 + 1.f);
      float h = th * q;
      out[(size_t)t * HDIM + row] = h;
      uint32_t dw = ((uint32_t)(t + 1) << 16) |
                    (uint32_t)__half_as_ushort(__float2half(h));
      const int pb = ((t + 1) & 1) << 10;
#pragma unroll
      for (int r = 0; r < 8; ++r) {
        if (r <= repmask) {
          __hip_atomic_store(&tagged[((size_t)r << 11) + pb + row], dw,
                             __ATOMIC_RELAXED, __HIP_MEMORY_SCOPE_AGENT);
        }
      }
    }
    // no trailing barrier: writes to hl[buf] at t+2 are gated by the poll for
    // t+2, which succeeds only after all leaders published t+2, which requires
    // every WG to have passed barrier(t+1), i.e. finished reading hl[buf] at t.
  }
}

extern "C" void kernel_launch(void* const* d_in, const int* in_sizes, int n_in,
                              void* d_out, int out_size, void* d_ws, size_t ws_size,
                              hipStream_t stream) {
  const float* x  = (const float*)d_in[0];
  const float* Uf = (const float*)d_in[1];
  const float* Wf = (const float*)d_in[2];
  const float* Bf = (const float*)d_in[3];
  const float* Ug = (const float*)d_in[4];
  const float* Wg = (const float*)d_in[5];
  const float* Bg = (const float*)d_in[6];
  const float* Uq = (const float*)d_in[7];
  const float* Wq = (const float*)d_in[8];
  const float* Bq = (const float*)d_in[9];
  const float* U  = (const float*)d_in[10];
  const float* W  = (const float*)d_in[11];
  const float* B  = (const float*)d_in[12];
  float* out = (float*)d_out;

  // ws layout: [0,32MB) xpre4 fp16 [4096][1024][4]; [32MB,40MB) wpack 2M dwords;
  // [40MB, +nrep*8KB) replicated tagged buffers. nrep sized from ws_size
  // (>=1 replica is proven to fit by prior passing rounds).
  char* ws = (char*)d_ws;
  __half* xpre4 = (__half*)ws;
  uint32_t* wpack = (uint32_t*)(ws + (size_t)32 * 1024 * 1024);
  uint32_t* tagged = (uint32_t*)(ws + (size_t)40 * 1024 * 1024);

  const size_t base = (size_t)40 * 1024 * 1024;
  size_t avail = (ws_size > base) ? (ws_size - base) : 8192;
  int cap = (int)(avail / 8192);
  if (cap < 1) cap = 1;
  if (cap > 8) cap = 8;
  int nrep = 1;
  while (nrep * 2 <= cap) nrep *= 2;
  const int repmask = nrep - 1;

  // gate order everywhere: 0=f(Uf,Wf,Bf) 1=c(U,W,B) 2=g(Ug,Wg,Bg) 3=q(Uq,Wq,Bq)
  convw<<<8192, 256, 0, stream>>>(Wf, W, Wg, Wq, wpack);
  zerok<<<64, 256, 0, stream>>>(tagged, nrep * 2048);
  gemmk<<<dim3(64, 64), 256, 0, stream>>>(x, Uf, U, Ug, Uq, Bf, B, Bg, Bq, xpre4);
  rnnk<<<NWG, 512, 0, stream>>>(wpack, xpre4, tagged, out, repmask);
}

// Round 9
// 12145.014 us; speedup vs baseline: 1.0761x; 1.0761x over previous
//
#include <hip/hip_runtime.h>
#include <hip/hip_fp16.h>
#include <stdint.h>

// LSTM-like scan, T=4096, E=1024, H=1024.
// Phase 1: xpre4[t][row][g] = (x @ U_g^T + B_g)  fp16, gate-interleaved
// Phase 2: persistent 64-WG x 512-thread kernel, 16 rows/WG, self-poll sync.
//   R9 change (vs R7): COALESCED PUBLISH. Leaders stage {tagged dword, f32 h}
//   in LDS; after a second barrier, wave0 lanes 0..15 store the WG's 16
//   tagged dwords as ONE full 64B line (and the 16 out floats as one line).
//   R1-vs-R7 evidence: scattered 4B publishes from 8 different waves cost
//   ~1.1us/step of IC partial-line write serialization; R1's wave-coalesced
//   publish was the only structural difference in its 1.69us/step sync.
//   Everything else identical to R7: per-step overlapped weight stream
//   (16x global_load_dwordx4 issued before the poll, drained by the poll's
//   vmcnt(0)), self-poll of own u64 tagged pair (sc0 sc1), one data barrier,
//   conflict-free lane-stride-32 LDS h reads, 64 v_dot2, 5-level shfl reduce.

#define T_STEPS 4096
#define HDIM 1024
#define NWG 64

typedef _Float16 half2v __attribute__((ext_vector_type(2)));
typedef uint32_t u32x4 __attribute__((ext_vector_type(4)));

__device__ __forceinline__ float dot2(uint32_t a, uint32_t b, float c) {
#if __has_builtin(__builtin_amdgcn_fdot2)
  return __builtin_amdgcn_fdot2(__builtin_bit_cast(half2v, a),
                                __builtin_bit_cast(half2v, b), c, false);
#else
  half2v av = __builtin_bit_cast(half2v, a);
  half2v bv = __builtin_bit_cast(half2v, b);
  return c + (float)av.x * (float)bv.x + (float)av.y * (float)bv.y;
#endif
}

__device__ __forceinline__ float sigf(float z) { return 1.f / (1.f + __expf(-z)); }

// ---- weight repack: gate f32 [1024][1024] x4 -> rnnk's coalesced layout ----
// dst dword index o = ((wg*16 + j)*512 + tid)*4 + e :
//   lane (wg,tid): k=tid&31, rloc=tid>>5, row=wg*16+rloc
//   logical weight dword i = 4j+e in [0,64): gate g=i>>4, n=i&15,
//   h-pair p = k + 32n  -> cols 2p, 2p+1 of gate-g weight row `row`.
__global__ __launch_bounds__(256) void convw(const float* __restrict__ w0,
                                             const float* __restrict__ w1,
                                             const float* __restrict__ w2,
                                             const float* __restrict__ w3,
                                             uint32_t* __restrict__ dst) {
  int o = blockIdx.x * 256 + threadIdx.x;  // 0 .. 2M-1
  int e = o & 3;
  int tid = (o >> 2) & 511;
  int j = (o >> 11) & 15;
  int wg = o >> 15;
  int i = 4 * j + e;
  int g = i >> 4, n = i & 15;
  int k = tid & 31, rloc = tid >> 5;
  int row = (wg << 4) + rloc;
  int col = ((k + (n << 5)) << 1);
  const float* src = g == 0 ? w0 : g == 1 ? w1 : g == 2 ? w2 : w3;
  float2 v = *(const float2*)(src + (size_t)row * 1024 + col);
  dst[o] = (uint32_t)__half_as_ushort(__float2half(v.x)) |
           ((uint32_t)__half_as_ushort(__float2half(v.y)) << 16);
}

// ---------------- zero the tagged h broadcast buffers (2 x 1024 dwords) --------
__global__ void zerok(uint32_t* __restrict__ p) {
  int i = blockIdx.x * 256 + threadIdx.x;
  if (i < 2048) p[i] = 0;
}

// ---------------- fp32 GEMM: xpre4[t][j][g] = x[t][:] . U_g[j][:] + B_g[j] -----
__global__ __launch_bounds__(256) void gemmk(
    const float* __restrict__ x,
    const float* __restrict__ u0, const float* __restrict__ u1,
    const float* __restrict__ u2, const float* __restrict__ u3,
    const float* __restrict__ b0, const float* __restrict__ b1,
    const float* __restrict__ b2, const float* __restrict__ b3,
    __half* __restrict__ xpre4) {
  __shared__ float As[64][33];
  __shared__ float Bs[64][33];
  const int tid = threadIdx.x;
  const int m0 = blockIdx.y * 64;
  const int n0 = blockIdx.x * 64;
  const int g = n0 >> 10;
  const float* Up = g == 0 ? u0 : g == 1 ? u1 : g == 2 ? u2 : u3;
  const float* Bp = g == 0 ? b0 : g == 1 ? b1 : g == 2 ? b2 : b3;
  const int j0 = n0 & 1023;
  const int tx = tid & 15, ty = tid >> 4;
  const int lr = tid >> 3, lc = (tid & 7) << 2;
  float acc[4][4] = {};
  for (int k0 = 0; k0 < 1024; k0 += 32) {
    float4 a0 = *(const float4*)&x[(size_t)(m0 + lr) * 1024 + k0 + lc];
    float4 a1 = *(const float4*)&x[(size_t)(m0 + lr + 32) * 1024 + k0 + lc];
    float4 c0 = *(const float4*)&Up[(size_t)(j0 + lr) * 1024 + k0 + lc];
    float4 c1 = *(const float4*)&Up[(size_t)(j0 + lr + 32) * 1024 + k0 + lc];
    __syncthreads();
    As[lr][lc + 0] = a0.x; As[lr][lc + 1] = a0.y; As[lr][lc + 2] = a0.z; As[lr][lc + 3] = a0.w;
    As[lr + 32][lc + 0] = a1.x; As[lr + 32][lc + 1] = a1.y; As[lr + 32][lc + 2] = a1.z; As[lr + 32][lc + 3] = a1.w;
    Bs[lr][lc + 0] = c0.x; Bs[lr][lc + 1] = c0.y; Bs[lr][lc + 2] = c0.z; Bs[lr][lc + 3] = c0.w;
    Bs[lr + 32][lc + 0] = c1.x; Bs[lr + 32][lc + 1] = c1.y; Bs[lr + 32][lc + 2] = c1.z; Bs[lr + 32][lc + 3] = c1.w;
    __syncthreads();
#pragma unroll
    for (int k = 0; k < 32; ++k) {
      float a0v = As[ty * 4 + 0][k], a1v = As[ty * 4 + 1][k];
      float a2v = As[ty * 4 + 2][k], a3v = As[ty * 4 + 3][k];
      float b0v = Bs[tx * 4 + 0][k], b1v = Bs[tx * 4 + 1][k];
      float b2v = Bs[tx * 4 + 2][k], b3v = Bs[tx * 4 + 3][k];
      acc[0][0] += a0v * b0v; acc[0][1] += a0v * b1v; acc[0][2] += a0v * b2v; acc[0][3] += a0v * b3v;
      acc[1][0] += a1v * b0v; acc[1][1] += a1v * b1v; acc[1][2] += a1v * b2v; acc[1][3] += a1v * b3v;
      acc[2][0] += a2v * b0v; acc[2][1] += a2v * b1v; acc[2][2] += a2v * b2v; acc[2][3] += a2v * b3v;
      acc[3][0] += a3v * b0v; acc[3][1] += a3v * b1v; acc[3][2] += a3v * b2v; acc[3][3] += a3v * b3v;
    }
  }
  // scatter epilogue: xpre4[(t*1024 + j)*4 + g]
#pragma unroll
  for (int i = 0; i < 4; ++i) {
    size_t rowi = (size_t)(m0 + ty * 4 + i);
#pragma unroll
    for (int j = 0; j < 4; ++j) {
      int jj = j0 + tx * 4 + j;
      float v = acc[i][j] + Bp[jj];
      xpre4[(rowi * 1024 + jj) * 4 + g] = __float2half(v);
    }
  }
}

// ---------------- persistent recurrence kernel --------------------------------
__global__ __launch_bounds__(512, 1) void rnnk(
    const uint32_t* __restrict__ wpack,  // [64][16][512][4] dwords (see convw)
    const __half* __restrict__ xpre4,    // [4096][1024][4] fp16
    uint32_t* tagged,                    // [2][1024] tagged h dwords
    float* __restrict__ out) {           // [4096][1024] f32
  __shared__ uint32_t hl[2][512];        // packed h pairs, linear
  __shared__ uint32_t hpubt[16];         // staged tagged dwords (this WG's rows)
  __shared__ float hpubf[16];            // staged f32 h
  const int wg = blockIdx.x;
  const int tid = threadIdx.x;
  const int wave = tid >> 6, lane = tid & 63;
  const int k = tid & 31;            // h-chunk lane
  const int rloc = tid >> 5;         // 0..15
  const int row = (wg << 4) + rloc;  // 0..1023
  const bool leader = (k == 0);

  const uint32_t* wbase = wpack + (((size_t)wg << 4) << 11) + (tid << 2);

  float s = 0.f;  // cell state (leader lanes only)

  for (int t = 0; t < T_STEPS; ++t) {
    const int buf = t & 1;

    // --- 1. issue this step's 16 weight loads (coalesced; no wait here) ---
    u32x4 wq[16];
#pragma unroll
    for (int j = 0; j < 16; ++j) {
      const uint32_t* p = wbase + (j << 11);
      asm volatile("global_load_dwordx4 %0, %1, off" : "=v"(wq[j]) : "v"(p));
    }

    // --- 2. leader prefetch of the 4 gate pre-activations (8B) ---
    float xf = 0.f, xc = 0.f, xg = 0.f, xq = 0.f;
    if (leader) {
      uint2 xv = *reinterpret_cast<const uint2*>(
          reinterpret_cast<const uint32_t*>(xpre4) +
          ((((size_t)t << 10) + row) << 1));
      __half2 lo = __builtin_bit_cast(__half2, xv.x);
      __half2 hi = __builtin_bit_cast(__half2, xv.y);
      xf = __half2float(lo.x); xc = __half2float(lo.y);
      xg = __half2float(hi.x); xq = __half2float(hi.y);
    }

    // --- 3. self-poll own tagged pair; vmcnt(0) also drains the weight loads ---
    {
      const unsigned long long* pp =
          reinterpret_cast<const unsigned long long*>(tagged + (buf << 10)) + tid;
      const uint32_t tg = (uint32_t)t;
      unsigned long long v;
      for (;;) {
        asm volatile(
            "global_load_dwordx2 %0, %1, off sc0 sc1\n\t"
            "s_waitcnt vmcnt(0)"
            : "=v"(v) : "v"(pp) : "memory");
        if ((((uint32_t)(v >> 16) & 0xffffu) == tg) && ((uint32_t)(v >> 48) == tg))
          break;
        __builtin_amdgcn_s_sleep(1);
      }
      hl[buf][tid] = (uint32_t)(v & 0xffffu) |
                     (((uint32_t)(v >> 32) & 0xffffu) << 16);
    }
    __syncthreads();  // B1: hl[buf] ready

    // --- 4. h pairs at lane-stride 32 (bank = k: conflict-free) + 64 dot2 ---
    uint32_t hp[16];
#pragma unroll
    for (int n = 0; n < 16; ++n) hp[n] = hl[buf][k + (n << 5)];

#define WD(g, n) (wq[((g)*16 + (n)) >> 2][((g)*16 + (n)) & 3])
    float a0 = 0.f, a1 = 0.f, a2 = 0.f, a3 = 0.f;
#pragma unroll
    for (int n = 0; n < 16; ++n) {
      a0 = dot2(WD(0, n), hp[n], a0);
      a1 = dot2(WD(1, n), hp[n], a1);
      a2 = dot2(WD(2, n), hp[n], a2);
      a3 = dot2(WD(3, n), hp[n], a3);
    }
#undef WD

    // --- 5. reduce across the 32 chunk-lanes (stays within 32-lane halves) ---
#pragma unroll
    for (int mk = 1; mk <= 16; mk <<= 1) {
      a0 += __shfl_xor(a0, mk);
      a1 += __shfl_xor(a1, mk);
      a2 += __shfl_xor(a2, mk);
      a3 += __shfl_xor(a3, mk);
    }

    // --- 6. leader epilogue: gates, s-update, h -> stage into LDS ---
    if (leader) {
      float f = sigf(a0 + xf);
      float cc = sigf(a1 + xc);
      float gg = sigf(a2 + xg);
      float q = sigf(a3 + xq);
      s = f * s + gg * cc;
      float e2 = __expf(2.f * s);  // s >= 0 always; inf -> th = 1
      float th = 1.f - 2.f / (e2 + 1.f);
      float h = th * q;
      hpubf[rloc] = h;
      hpubt[rloc] = ((uint32_t)(t + 1) << 16) |
                    (uint32_t)__half_as_ushort(__float2half(h));
    }
    __syncthreads();  // B2: hpub ready

    // --- 7. COALESCED publish: wave0 lanes 0..15 -> one 64B tagged line +
    //        one 64B out line (vs 16 scattered partial-line stores). ---
    if (wave == 0 && lane < 16) {
      uint32_t dw = hpubt[lane];
      float hv = hpubf[lane];
      const int pb = ((t + 1) & 1) << 10;
      __hip_atomic_store(&tagged[pb + (wg << 4) + lane], dw,
                         __ATOMIC_RELAXED, __HIP_MEMORY_SCOPE_AGENT);
      out[(size_t)t * HDIM + (wg << 4) + lane] = hv;
    }
    // no trailing barrier needed:
    //  - hl[buf] rewritten at t+2, gated by poll(t+2) <- publishes(t+2) <- B2(t+1)
    //  - hpub rewritten at t+1 only after B1(t+1), which wave0 reaches only
    //    after its poll(t+1) succeeds, i.e. after it read hpub(t) and stored.
  }
}

extern "C" void kernel_launch(void* const* d_in, const int* in_sizes, int n_in,
                              void* d_out, int out_size, void* d_ws, size_t ws_size,
                              hipStream_t stream) {
  const float* x  = (const float*)d_in[0];
  const float* Uf = (const float*)d_in[1];
  const float* Wf = (const float*)d_in[2];
  const float* Bf = (const float*)d_in[3];
  const float* Ug = (const float*)d_in[4];
  const float* Wg = (const float*)d_in[5];
  const float* Bg = (const float*)d_in[6];
  const float* Uq = (const float*)d_in[7];
  const float* Wq = (const float*)d_in[8];
  const float* Bq = (const float*)d_in[9];
  const float* U  = (const float*)d_in[10];
  const float* W  = (const float*)d_in[11];
  const float* B  = (const float*)d_in[12];
  float* out = (float*)d_out;

  // ws layout: [0,32MB) xpre4 fp16 [4096][1024][4]; [32MB,40MB) wpack 2M dwords;
  // [40MB,+8KB) tagged h dwords [2][1024].
  char* ws = (char*)d_ws;
  __half* xpre4 = (__half*)ws;
  uint32_t* wpack = (uint32_t*)(ws + (size_t)32 * 1024 * 1024);
  uint32_t* tagged = (uint32_t*)(ws + (size_t)40 * 1024 * 1024);

  // gate order everywhere: 0=f(Uf,Wf,Bf) 1=c(U,W,B) 2=g(Ug,Wg,Bg) 3=q(Uq,Wq,Bq)
  convw<<<8192, 256, 0, stream>>>(Wf, W, Wg, Wq, wpack);
  zerok<<<8, 256, 0, stream>>>(tagged);
  gemmk<<<dim3(64, 64), 256, 0, stream>>>(x, Uf, U, Ug, Uq, Bf, B, Bg, Bq, xpre4);
  rnnk<<<NWG, 512, 0, stream>>>(wpack, xpre4, tagged, out);
}